// Round 12
// baseline (240.247 us; speedup 1.0000x reference)
//
#include <hip/hip_runtime.h>
#include <math.h>

#define BB 16
#define HH 8
#define SS 512
#define FF 512
#define DD 64
#define RANKK 12
#define KTOP 51
#define ROWS 8

typedef __attribute__((ext_vector_type(8))) short bf16x8;
typedef __attribute__((ext_vector_type(4))) float f32x4;

// ---------- bf16 helpers (explicit RNE, deterministic) ----------
__device__ __forceinline__ unsigned short f2bf(float x){
  unsigned u = __float_as_uint(x);
  return (unsigned short)((u + 0x7FFFu + ((u>>16)&1u)) >> 16);
}
__device__ __forceinline__ float bf2f(unsigned short h){
  return __uint_as_float(((unsigned)h)<<16);
}

// monotonic float->uint order mapping (no NaNs in this problem)
__device__ __forceinline__ unsigned f2ord(float x){
  unsigned u = __float_as_uint(x);
  return (u & 0x80000000u) ? ~u : (u | 0x80000000u);
}

// One wave owns one row of 512 values (8 per lane, f = lane*8+j).
// Early exit when cnt==KTOP is EXACT (kept set identical).  (FROZEN)
__device__ __forceinline__ void topk_softmax8(float (&a)[8]){
  unsigned key[8];
#pragma unroll
  for (int j=0;j<8;++j) key[j] = f2ord(a[j]);
  unsigned T = 0u;
#pragma unroll
  for (int bit=31; bit>=0; --bit){
    unsigned Tp = T | (1u<<bit);
    int cnt = 0;
#pragma unroll
    for (int j=0;j<8;++j){
      unsigned long long bl = __ballot(key[j] >= Tp);
      cnt += __popcll(bl);
    }
    if (cnt >= KTOP) T = Tp;
    if (cnt == KTOP) break;            // wave-uniform exact early exit
  }
  float m = a[0];
#pragma unroll
  for (int j=1;j<8;++j) m = fmaxf(m, a[j]);
#pragma unroll
  for (int off=32; off>=1; off>>=1) m = fmaxf(m, __shfl_xor(m, off));
  float sum = 0.f;
#pragma unroll
  for (int j=0;j<8;++j){
    float e = (key[j] >= T) ? expf(a[j]-m) : 0.f;
    a[j] = e; sum += e;
  }
#pragma unroll
  for (int off=32; off>=1; off>>=1) sum += __shfl_xor(sum, off);
  float inv = 1.f/sum;
#pragma unroll
  for (int j=0;j<8;++j) a[j] *= inv;
}

// ---------------------------------------------------------------------------
// Fused prologue: blocks [0,128): transpose pass + score pass (verbatim);
// blocks [128,640): alpha body (verbatim). One launch.  (FROZEN bits)
// ---------------------------------------------------------------------------
__global__ __launch_bounds__(512) void k_prep_all(
    const float* __restrict__ values, const float* __restrict__ temp,
    const float* __restrict__ ln_w, const float* __restrict__ ln_b,
    const float* __restrict__ alpha, float* __restrict__ score_ln,
    unsigned short* __restrict__ hiP, unsigned short* __restrict__ loP,
    float* __restrict__ A_soft)
{
  const int tid = threadIdx.x, w = tid >> 6, lane = tid & 63;
  if (blockIdx.x >= BB*HH){
    const int row = (int)(blockIdx.x - BB*HH) * ROWS + w;
    const float SCALE = (float)(1.0/sqrt((double)FF));
    const float* ar = alpha + (size_t)row*FF + lane*8;
    float4 v0 = *(const float4*)ar;
    float4 v1 = *(const float4*)(ar+4);
    float a[8] = {v0.x*SCALE, v0.y*SCALE, v0.z*SCALE, v0.w*SCALE,
                  v1.x*SCALE, v1.y*SCALE, v1.z*SCALE, v1.w*SCALE};
    topk_softmax8(a);
    float* orow = A_soft + (size_t)row*FF + lane*8;
    *(float4*)orow     = make_float4(a[0],a[1],a[2],a[3]);
    *(float4*)(orow+4) = make_float4(a[4],a[5],a[6],a[7]);
    return;
  }
  __shared__ float tile[64][65];
  __shared__ float s_e[FF];
  __shared__ float ps[8], ps2[8];
  const int b = blockIdx.x / HH, h = blockIdx.x % HH;
  const float* vb = values + ((size_t)b*FF*HH + h)*DD;

  for (int c=0;c<8;++c){
#pragma unroll
    for (int p=0;p<8;++p){
      const int fi = p*8 + w;
      const int f  = c*64 + fi;
      tile[fi][lane] = vb[(size_t)f*HH*DD + lane];
    }
    __syncthreads();
    {
      const int d  = w*8 + (lane>>3);
      const int fj = (lane&7)*8;
      unsigned short hs[8], ls[8];
#pragma unroll
      for (int j=0;j<8;++j){
        float x = tile[fj+j][d];
        hs[j] = f2bf(x);
        ls[j] = f2bf(x - bf2f(hs[j]));
      }
      uint4 H4, L4;
      H4.x=(unsigned)hs[0]|((unsigned)hs[1]<<16); H4.y=(unsigned)hs[2]|((unsigned)hs[3]<<16);
      H4.z=(unsigned)hs[4]|((unsigned)hs[5]<<16); H4.w=(unsigned)hs[6]|((unsigned)hs[7]<<16);
      L4.x=(unsigned)ls[0]|((unsigned)ls[1]<<16); L4.y=(unsigned)ls[2]|((unsigned)ls[3]<<16);
      L4.z=(unsigned)ls[4]|((unsigned)ls[5]<<16); L4.w=(unsigned)ls[6]|((unsigned)ls[7]<<16);
      const size_t base = ((size_t)blockIdx.x*DD + d)*FF + c*64 + fj;
      *(uint4*)(hiP + base) = H4;
      *(uint4*)(loP + base) = L4;
    }
    __syncthreads();
  }

  for (int i=0;i<FF/8;++i){
    int f = w*(FF/8) + i;
    float v = vb[(size_t)f*HH*DD + lane];
    float e = v*v;
#pragma unroll
    for (int off=32; off>=1; off>>=1) e += __shfl_xor(e, off);
    if (lane==0) s_e[f] = e * (1.0f/DD);
  }
  __syncthreads();
  float e = s_e[tid];
  float se = e, se2 = e*e;
#pragma unroll
  for (int off=32; off>=1; off>>=1){ se += __shfl_xor(se, off); se2 += __shfl_xor(se2, off); }
  if (lane==0){ ps[w]=se; ps2[w]=se2; }
  __syncthreads();
  float S1=0.f, S2=0.f;
#pragma unroll
  for (int g=0; g<8; ++g){ S1 += ps[g]; S2 += ps2[g]; }
  float meanE = S1 * (1.0f/FF);
  float rms = fmaxf(sqrtf(meanE), 1e-6f);
  float t = temp[h];
  float gain = (t > 20.f) ? t : log1pf(expf(t));
  float c = gain / rms;
  float mu = c * meanE;
  float var = c*c*(S2*(1.0f/FF) - meanE*meanE);
  float inv = rsqrtf(var + 1e-5f);
  score_ln[(size_t)blockIdx.x*FF + tid] = (c*e - mu)*inv*ln_w[tid] + ln_b[tid];
}

// Kernel: score only (deep-fallback path)
__global__ __launch_bounds__(512) void k_score(const float* __restrict__ values,
    const float* __restrict__ temp, const float* __restrict__ ln_w,
    const float* __restrict__ ln_b, float* __restrict__ score_ln)
{
  const int b = blockIdx.x / HH, h = blockIdx.x % HH;
  const int tid = threadIdx.x, w = tid >> 6, lane = tid & 63;
  __shared__ float s_e[FF];
  __shared__ float ps[8], ps2[8];
  const float* vb = values + ((size_t)b*FF*HH + h)*DD;
  for (int i=0;i<FF/8;++i){
    int f = w*(FF/8) + i;
    float v = vb[(size_t)f*HH*DD + lane];
    float e = v*v;
#pragma unroll
    for (int off=32; off>=1; off>>=1) e += __shfl_xor(e, off);
    if (lane==0) s_e[f] = e * (1.0f/DD);
  }
  __syncthreads();
  float e = s_e[tid];
  float se = e, se2 = e*e;
#pragma unroll
  for (int off=32; off>=1; off>>=1){ se += __shfl_xor(se, off); se2 += __shfl_xor(se2, off); }
  if (lane==0){ ps[w]=se; ps2[w]=se2; }
  __syncthreads();
  float S1=0.f, S2=0.f;
#pragma unroll
  for (int g=0; g<8; ++g){ S1 += ps[g]; S2 += ps2[g]; }
  float meanE = S1 * (1.0f/FF);
  float rms = fmaxf(sqrtf(meanE), 1e-6f);
  float t = temp[h];
  float gain = (t > 20.f) ? t : log1pf(expf(t));
  float c = gain / rms;
  float mu = c * meanE;
  float var = c*c*(S2*(1.0f/FF) - meanE*meanE);
  float inv = rsqrtf(var + 1e-5f);
  score_ln[(size_t)blockIdx.x*FF + tid] = (c*e - mu)*inv*ln_w[tid] + ln_b[tid];
}

// ---------- phase-1 helper (FROZEN — validated bits) ----------
__device__ __forceinline__ void build_mix_row(int bh, int h, int s, int lane,
    const float* __restrict__ score_ln, const float* __restrict__ gamma,
    const float* __restrict__ U, const float* __restrict__ V,
    const float* __restrict__ A_soft, float4& m0, float4& m1)
{
  const int f0 = lane*8;
  const float* sr = score_ln + (size_t)bh*FF + f0;
  float4 sv0 = *(const float4*)sr;
  float4 sv1 = *(const float4*)(sr+4);
  const float g = gamma[h*SS + s];
  float dl[8] = {sv0.x+g, sv0.y+g, sv0.z+g, sv0.w+g,
                 sv1.x+g, sv1.y+g, sv1.z+g, sv1.w+g};
  const float* Ur = U + ((size_t)h*SS + s)*RANKK;
  const float* Vh = V + (size_t)h*RANKK*FF + f0;
#pragma unroll
  for (int r=0;r<RANKK;++r){
    float u = Ur[r];
    float4 b0 = *(const float4*)(Vh + r*FF);
    float4 b1 = *(const float4*)(Vh + r*FF + 4);
    dl[0] += u*b0.x; dl[1] += u*b0.y; dl[2] += u*b0.z; dl[3] += u*b0.w;
    dl[4] += u*b1.x; dl[5] += u*b1.y; dl[6] += u*b1.z; dl[7] += u*b1.w;
  }
  topk_softmax8(dl);
  const float* arow = A_soft + ((size_t)h*SS + s)*FF + f0;
  float4 a0 = *(const float4*)arow;
  float4 a1 = *(const float4*)(arow+4);
  m0 = make_float4(dl[0]+a0.x, dl[1]+a0.y, dl[2]+a0.z, dl[3]+a0.w);
  m1 = make_float4(dl[4]+a1.x, dl[5]+a1.y, dl[6]+a1.z, dl[7]+a1.w);
}

// ---------- producer body: one wave -> one mix row -> global bf16 hi/lo ----
template<int NBC>
__device__ __forceinline__ void mix_body(int bid, const float* __restrict__ gamma,
    const float* __restrict__ U, const float* __restrict__ V,
    const float* __restrict__ score_ln, const float* __restrict__ A_soft,
    unsigned short* __restrict__ mixH, unsigned short* __restrict__ mixL,
    int b0, int tid)
{
  const int w = tid>>6, lane = tid&63;
  const int rid = bid*8 + w;          // ((h*SS + s)*NBC + bi), h-major
  const int bi  = rid % NBC;
  const int hs  = rid / NBC;
  const int h   = hs >> 9;
  const int s   = hs & 511;
  float4 m0, m1;
  build_mix_row((b0+bi)*HH + h, h, s, lane, score_ln, gamma, U, V, A_soft, m0, m1);
  float xs[8] = {m0.x,m0.y,m0.z,m0.w,m1.x,m1.y,m1.z,m1.w};
  unsigned short hv[8], lv[8];
#pragma unroll
  for (int j=0;j<8;++j){
    hv[j] = f2bf(xs[j]);
    lv[j] = f2bf(xs[j] - bf2f(hv[j]));
  }
  uint4 H4, L4;
  H4.x=(unsigned)hv[0]|((unsigned)hv[1]<<16); H4.y=(unsigned)hv[2]|((unsigned)hv[3]<<16);
  H4.z=(unsigned)hv[4]|((unsigned)hv[5]<<16); H4.w=(unsigned)hv[6]|((unsigned)hv[7]<<16);
  L4.x=(unsigned)lv[0]|((unsigned)lv[1]<<16); L4.y=(unsigned)lv[2]|((unsigned)lv[3]<<16);
  L4.z=(unsigned)lv[4]|((unsigned)lv[5]<<16); L4.w=(unsigned)lv[6]|((unsigned)lv[7]<<16);
  const size_t base = ((size_t)(bi*HH + h)*SS + s)*FF + lane*8;
  *(uint4*)(mixH + base) = H4;
  *(uint4*)(mixL + base) = L4;
}

// ---------- consumer body: pure GEMM 128s x 64d per block ----------
// wave w: rows [s0+w*16, +16), all 64 d (4 n-tiles); MFMA chain t-ascending,
// acc0/acc1 separation and order IDENTICAL to prior validated kernels.
template<int NBC>
__device__ __forceinline__ void gemm_body(int bid,
    const unsigned short* __restrict__ mixH, const unsigned short* __restrict__ mixL,
    const unsigned short* __restrict__ hiP, const unsigned short* __restrict__ loP,
    float* __restrict__ out, int b0, float* lds, int tid)
{
  const int stile = bid & 3;
  const int g  = bid >> 2;            // h*NBC + bi
  const int h  = g / NBC;
  const int bi = g % NBC;
  const int b  = b0 + bi;
  const int s0 = stile*128;
  const int w = tid>>6, lane = tid&63;
  const int fr = (lane>>4)*8;

  const size_t abase = ((size_t)(bi*HH + h)*SS + s0 + w*16 + (lane&15))*FF + fr;
  const unsigned short* mh = mixH + abase;
  const unsigned short* ml = mixL + abase;
  const size_t bbase = ((size_t)(b*HH + h)*DD + (lane&15))*FF + fr;
  const unsigned short* bh0 = hiP + bbase;
  const unsigned short* bl0 = loP + bbase;

  f32x4 c0[4] = {{0,0,0,0},{0,0,0,0},{0,0,0,0},{0,0,0,0}};
  f32x4 c1[4] = {{0,0,0,0},{0,0,0,0},{0,0,0,0},{0,0,0,0}};

#pragma unroll
  for (int t=0;t<16;++t){
    bf16x8 ah = *(const bf16x8*)(mh + t*32);
    bf16x8 al = *(const bf16x8*)(ml + t*32);
#pragma unroll
    for (int nt=0;nt<4;++nt){
      bf16x8 bhv = *(const bf16x8*)(bh0 + (size_t)nt*16*FF + t*32);
      bf16x8 blv = *(const bf16x8*)(bl0 + (size_t)nt*16*FF + t*32);
      c0[nt] = __builtin_amdgcn_mfma_f32_16x16x32_bf16(ah, bhv, c0[nt], 0, 0, 0);
      c1[nt] = __builtin_amdgcn_mfma_f32_16x16x32_bf16(al, bhv, c1[nt], 0, 0, 0);
      c1[nt] = __builtin_amdgcn_mfma_f32_16x16x32_bf16(ah, blv, c1[nt], 0, 0, 0);
    }
  }

  // epilogue: stage [128][64] f32 in LDS, write full 128B lines
  const int m0r = (lane>>4)*4;
#pragma unroll
  for (int nt=0;nt<4;++nt){
    const int d = nt*16 + (lane&15);
#pragma unroll
    for (int r=0;r<4;++r)
      lds[(w*16 + m0r + r)*64 + d] = c0[nt][r] + c1[nt][r];
  }
  __syncthreads();
#pragma unroll
  for (int p=0;p<4;++p){
    const int row = p*32 + (tid>>4);
    const int col = (tid&15)*4;
    *(float4*)&out[(((size_t)b*SS + s0 + row)*HH + h)*DD + col]
        = *(const float4*)&lds[row*64 + col];
  }
}

template<int NBC>
__global__ __launch_bounds__(512, 4) void k_mix(const float* __restrict__ gamma,
    const float* __restrict__ U, const float* __restrict__ V,
    const float* __restrict__ score_ln, const float* __restrict__ A_soft,
    unsigned short* __restrict__ mixH, unsigned short* __restrict__ mixL, int b0)
{
  const int nwg = NBC*HH*SS/8;
  const int bid = (blockIdx.x & 7)*(nwg/8) + (blockIdx.x >> 3);
  mix_body<NBC>(bid, gamma, U, V, score_ln, A_soft, mixH, mixL, b0, threadIdx.x);
}

template<int NBC>
__global__ __launch_bounds__(512, 3) void k_gemm(
    const unsigned short* __restrict__ mixH, const unsigned short* __restrict__ mixL,
    const unsigned short* __restrict__ hiP, const unsigned short* __restrict__ loP,
    float* __restrict__ out, int b0)
{
  __shared__ float lds[128*64];
  const int NC = NBC*32;
  const int bid = (blockIdx.x & 7)*(NC/8) + (blockIdx.x >> 3);
  gemm_body<NBC>(bid, mixH, mixL, hiP, loP, out, b0, lds, threadIdx.x);
}

// Fused: blocks [0,NC) consume chunk c-1; blocks [NC,NC+NP) produce chunk c.
template<int NBC>
__global__ __launch_bounds__(512, 3) void k_fused(const float* __restrict__ gamma,
    const float* __restrict__ U, const float* __restrict__ V,
    const float* __restrict__ score_ln, const float* __restrict__ A_soft,
    unsigned short* __restrict__ mixHw, unsigned short* __restrict__ mixLw, int b0p,
    const unsigned short* __restrict__ mixHr, const unsigned short* __restrict__ mixLr,
    int b0c, const unsigned short* __restrict__ hiP, const unsigned short* __restrict__ loP,
    float* __restrict__ out)
{
  __shared__ float lds[128*64];
  const int NC = NBC*32;
  if ((int)blockIdx.x < NC){
    const int bid = (blockIdx.x & 7)*(NC/8) + (blockIdx.x >> 3);
    gemm_body<NBC>(bid, mixHr, mixLr, hiP, loP, out, b0c, lds, threadIdx.x);
  } else {
    const int pidx = blockIdx.x - NC;
    const int NP = NBC*HH*SS/8;
    const int bid = (pidx & 7)*(NP/8) + (pidx >> 3);
    mix_body<NBC>(bid, gamma, U, V, score_ln, A_soft, mixHw, mixLw, b0p, threadIdx.x);
  }
}

// ---------- r8 fallback: staged MFMA kernel (proven 144us) ----------
__device__ __forceinline__ void gload16(const void* g, void* l){
  __builtin_amdgcn_global_load_lds(
      (const __attribute__((address_space(1))) unsigned int*)g,
      (__attribute__((address_space(3))) unsigned int*)l, 16, 0, 0);
}

template<int NB>
__global__ __launch_bounds__(512, 4) void k_mfma_t(
    const unsigned short* __restrict__ hiP, const unsigned short* __restrict__ loP,
    const float* __restrict__ gamma, const float* __restrict__ U,
    const float* __restrict__ V, const float* __restrict__ score_ln,
    const float* __restrict__ A_soft, float* __restrict__ out, int b0)
{
  __shared__ __align__(16) unsigned char Abuf[65536];
  __shared__ __align__(16) unsigned char Bbuf[2][8192];
  const int nwg = HH*NB*16;
  const int bid = (blockIdx.x & 7)*(nwg/8) + (blockIdx.x >> 3);
  const int grp  = bid >> 4;
  const int sblk = bid & 15;
  const int h    = grp / NB;
  const int bloc = grp % NB;
  const int b    = b0 + bloc;
  const int s0   = sblk*32;
  const int bh   = b*HH + h;
  const int tid = threadIdx.x, w = tid>>6, lane = tid&63;

  const size_t pbBase = (size_t)(bloc*HH + h)*DD*FF;
  const int dw  = tid >> 3;
  const int s8p = tid & 7;
  const int s8  = s8p ^ (dw & 7);
  const unsigned short* sp = ((s8 & 4) ? loP : hiP)
                             + pbBase + (size_t)dw*FF + (size_t)(s8 & 3)*8;
  gload16(sp, &Bbuf[0][(unsigned)w<<10]);

#pragma unroll
  for (int i=0;i<4;++i){
    const int sl = w*4 + i;
    float4 m0, m1;
    build_mix_row(bh, h, s0+sl, lane, score_ln, gamma, U, V, A_soft, m0, m1);
    float xs[8] = {m0.x,m0.y,m0.z,m0.w,m1.x,m1.y,m1.z,m1.w};
    unsigned short hv[8], lv[8];
#pragma unroll
    for (int j=0;j<8;++j){
      hv[j] = f2bf(xs[j]);
      lv[j] = f2bf(xs[j] - bf2f(hv[j]));
    }
    uint4 H4, L4;
    H4.x=(unsigned)hv[0]|((unsigned)hv[1]<<16); H4.y=(unsigned)hv[2]|((unsigned)hv[3]<<16);
    H4.z=(unsigned)hv[4]|((unsigned)hv[5]<<16); H4.w=(unsigned)hv[6]|((unsigned)hv[7]<<16);
    L4.x=(unsigned)lv[0]|((unsigned)lv[1]<<16); L4.y=(unsigned)lv[2]|((unsigned)lv[3]<<16);
    L4.z=(unsigned)lv[4]|((unsigned)lv[5]<<16); L4.w=(unsigned)lv[6]|((unsigned)lv[7]<<16);
    const unsigned byt = (unsigned)(sl*1024 + lane*16) ^ (unsigned)((sl&15)<<4);
    *(uint4*)(Abuf + byt)          = H4;
    *(uint4*)(Abuf + 32768 + byt)  = L4;
  }
  __syncthreads();

  const int stile = w>>2, ntile = w&3;
  const int srow  = stile*16 + (lane&15);
  const unsigned sw = (unsigned)((lane&15)<<4);
  const unsigned a0off = (unsigned)(srow*1024 + ((lane>>4)*16));
  const int d    = ntile*16 + (lane&15);
  const int sgr  = lane>>4;
  const unsigned offH = (unsigned)(d*128 + ((sgr    ) ^ (d&7))*16);
  const unsigned offL = (unsigned)(d*128 + ((sgr + 4) ^ (d&7))*16);

  f32x4 acc0 = {0.f,0.f,0.f,0.f};
  f32x4 acc1 = {0.f,0.f,0.f,0.f};

#pragma unroll
  for (int t=0;t<16;++t){
    if (t > 0){
      asm volatile("s_waitcnt vmcnt(0) lgkmcnt(0)" ::: "memory");
      __builtin_amdgcn_s_barrier();
    }
    if (t < 15)
      gload16(sp + (size_t)(t+1)*32, &Bbuf[(t+1)&1][(unsigned)w<<10]);
    const unsigned ax = (a0off + (unsigned)(t*64)) ^ sw;
    bf16x8 ah = *(const bf16x8*)(Abuf + ax);
    bf16x8 al = *(const bf16x8*)(Abuf + 32768 + ax);
    const unsigned char* bb = Bbuf[t&1];
    bf16x8 bhv = *(const bf16x8*)(bb + offH);
    bf16x8 blv = *(const bf16x8*)(bb + offL);
    __builtin_amdgcn_s_setprio(1);
    acc0 = __builtin_amdgcn_mfma_f32_16x16x32_bf16(ah, bhv, acc0, 0, 0, 0);
    acc1 = __builtin_amdgcn_mfma_f32_16x16x32_bf16(al, bhv, acc1, 0, 0, 0);
    acc1 = __builtin_amdgcn_mfma_f32_16x16x32_bf16(ah, blv, acc1, 0, 0, 0);
    __builtin_amdgcn_s_setprio(0);
  }

  const int m0r = stile*16 + (lane>>4)*4;
#pragma unroll
  for (int r=0;r<4;++r){
    const int s = s0 + m0r + r;
    __builtin_nontemporal_store(acc0[r] + acc1[r],
        &out[(((size_t)b*SS + s)*HH + h)*DD + d]);
  }
}

// ---------- deep fallback: r1 LDS-broadcast kernel ----------
__global__ __launch_bounds__(512) void k_main_lds(const float* __restrict__ values,
    const float* __restrict__ alpha, const float* __restrict__ gamma,
    const float* __restrict__ U, const float* __restrict__ V,
    const float* __restrict__ score_ln, float* __restrict__ out)
{
  const int nwg = BB*HH*(SS/ROWS);
  const int bid = (blockIdx.x & 7)*(nwg/8) + (blockIdx.x >> 3);
  const int blocksPerBH = SS / ROWS;
  const int bh = bid / blocksPerBH;
  const int s0 = (bid % blocksPerBH) * ROWS;
  const int b = bh / HH, h = bh % HH;
  const int tid = threadIdx.x, w = tid >> 6, lane = tid & 63;
  __shared__ float smix[ROWS][FF];

  {
    const int s = s0 + w;
    const int f0 = lane*8;
    const float* sr = score_ln + (size_t)bh*FF + f0;
    float4 sv0 = *(const float4*)sr;
    float4 sv1 = *(const float4*)(sr+4);
    const float g = gamma[h*SS + s];
    float dl[8] = {sv0.x+g, sv0.y+g, sv0.z+g, sv0.w+g,
                   sv1.x+g, sv1.y+g, sv1.z+g, sv1.w+g};
    const float* Ur = U + ((size_t)h*SS + s)*RANKK;
    const float* Vh = V + (size_t)h*RANKK*FF + f0;
#pragma unroll
    for (int r=0;r<RANKK;++r){
      float u = Ur[r];
      float4 b0 = *(const float4*)(Vh + r*FF);
      float4 b1 = *(const float4*)(Vh + r*FF + 4);
      dl[0] += u*b0.x; dl[1] += u*b0.y; dl[2] += u*b0.z; dl[3] += u*b0.w;
      dl[4] += u*b1.x; dl[5] += u*b1.y; dl[6] += u*b1.z; dl[7] += u*b1.w;
    }
    topk_softmax8(dl);
    const float SCALE = (float)(1.0/sqrt((double)FF));
    const float* arow = alpha + ((size_t)h*SS + s)*FF + f0;
    float4 a0 = *(const float4*)arow;
    float4 a1 = *(const float4*)(arow+4);
    float ap[8] = {a0.x*SCALE, a0.y*SCALE, a0.z*SCALE, a0.w*SCALE,
                   a1.x*SCALE, a1.y*SCALE, a1.z*SCALE, a1.w*SCALE};
    topk_softmax8(ap);
    float4 m0 = make_float4(dl[0]+ap[0], dl[1]+ap[1], dl[2]+ap[2], dl[3]+ap[3]);
    float4 m1 = make_float4(dl[4]+ap[4], dl[5]+ap[5], dl[6]+ap[6], dl[7]+ap[7]);
    *(float4*)&smix[w][f0]   = m0;
    *(float4*)&smix[w][f0+4] = m1;
  }
  __syncthreads();

  float acc[ROWS] = {0,0,0,0,0,0,0,0};
  {
    const float* vp = values + (size_t)b*FF*HH*DD + (size_t)h*DD + lane;
#pragma unroll
    for (int i=0;i<16;++i){
      const int f0 = w*64 + i*4;
      float x0 = vp[(size_t)(f0+0)*HH*DD];
      float x1 = vp[(size_t)(f0+1)*HH*DD];
      float x2 = vp[(size_t)(f0+2)*HH*DD];
      float x3 = vp[(size_t)(f0+3)*HH*DD];
#pragma unroll
      for (int r=0;r<ROWS;++r){
        float4 m = *(const float4*)&smix[r][f0];
        acc[r] += m.x*x0 + m.y*x1 + m.z*x2 + m.w*x3;
      }
    }
  }
  __syncthreads();

  float* red = &smix[0][0];
#pragma unroll
  for (int r=0;r<ROWS;++r) red[(w*ROWS + r)*64 + lane] = acc[r];
  __syncthreads();
  {
    const int r = w, dd = lane;
    float sum = 0.f;
#pragma unroll
    for (int g=0; g<8; ++g) sum += red[(g*ROWS + r)*64 + dd];
    out[(((size_t)b*SS + s0 + r)*HH + h)*DD + dd] = sum;
  }
}

// ---------- host-side paired launcher ----------
template<int NBC>
static void launch_paired(const float* gamma, const float* U, const float* V,
    float* score_ln, float* A_soft, unsigned short* hiP, unsigned short* loP,
    unsigned short* mixBase, float* out, hipStream_t stream)
{
  const int nch = BB/NBC;
  const size_t mixE = (size_t)NBC*HH*SS*FF;     // elems per plane
  unsigned short* mH[2] = {mixBase,              mixBase + 2*mixE};
  unsigned short* mL[2] = {mixBase + mixE,       mixBase + 3*mixE};
  const int NP = NBC*HH*SS/8, NC = NBC*32;

  hipLaunchKernelGGL((k_mix<NBC>), dim3(NP), dim3(512), 0, stream,
                     gamma, U, V, score_ln, A_soft, mH[0], mL[0], 0);
  for (int c=1; c<nch; ++c){
    hipLaunchKernelGGL((k_fused<NBC>), dim3(NC+NP), dim3(512), 0, stream,
                       gamma, U, V, score_ln, A_soft,
                       mH[c&1], mL[c&1], c*NBC,
                       mH[(c-1)&1], mL[(c-1)&1], (c-1)*NBC, hiP, loP, out);
  }
  hipLaunchKernelGGL((k_gemm<NBC>), dim3(NC), dim3(512), 0, stream,
                     mH[(nch-1)&1], mL[(nch-1)&1], hiP, loP, out, (nch-1)*NBC);
}

extern "C" void kernel_launch(void* const* d_in, const int* in_sizes, int n_in,
                              void* d_out, int out_size, void* d_ws, size_t ws_size,
                              hipStream_t stream) {
  const float* values = (const float*)d_in[0];
  const float* alpha  = (const float*)d_in[1];
  const float* temp   = (const float*)d_in[2];
  const float* gamma  = (const float*)d_in[3];
  const float* U      = (const float*)d_in[4];
  const float* V      = (const float*)d_in[5];
  const float* ln_w   = (const float*)d_in[6];
  const float* ln_b   = (const float*)d_in[7];
  float* out = (float*)d_out;
  float* ws  = (float*)d_ws;

  const size_t scoreN = (size_t)BB*HH*FF;             // 65,536 f
  const size_t alphaN = (size_t)HH*SS*FF;             // 2,097,152 f
  const size_t planeN = (size_t)BB*HH*DD*FF;          // 4,194,304 us/plane

  float* score_ln = ws;
  float* A_soft   = ws + scoreN;
  unsigned short* hiP = (unsigned short*)(ws + scoreN + alphaN);
  unsigned short* loP = hiP + planeN;
  unsigned short* mixBase = loP + planeN;

  const size_t baseB = scoreN*4 + alphaN*4 + 2*planeN*2;   // 25.4 MB
  auto needP = [&](int nbc)->size_t{ return baseB + (size_t)nbc*4*HH*SS*FF*2; };
  const size_t needS1 = baseB + (size_t)2*HH*SS*FF*2;      // serial 1-chunk

  if (ws_size >= needS1){
    hipLaunchKernelGGL(k_prep_all, dim3(BB*HH + HH*SS/ROWS), dim3(512), 0, stream,
                       values, temp, ln_w, ln_b, alpha, score_ln, hiP, loP, A_soft);
    if (ws_size >= needP(4)){
      launch_paired<4>(gamma, U, V, score_ln, A_soft, hiP, loP, mixBase, out, stream);
    } else if (ws_size >= needP(2)){
      launch_paired<2>(gamma, U, V, score_ln, A_soft, hiP, loP, mixBase, out, stream);
    } else if (ws_size >= needP(1)){
      launch_paired<1>(gamma, U, V, score_ln, A_soft, hiP, loP, mixBase, out, stream);
    } else {
      // serial single-buffer, 16 chunks of 1
      const size_t mixE = (size_t)HH*SS*FF;
      unsigned short* mH = mixBase;
      unsigned short* mL = mixBase + mixE;
      for (int c=0;c<BB;++c){
        hipLaunchKernelGGL((k_mix<1>), dim3(HH*SS/8), dim3(512), 0, stream,
                           gamma, U, V, score_ln, A_soft, mH, mL, c);
        hipLaunchKernelGGL((k_gemm<1>), dim3(32), dim3(512), 0, stream,
                           mH, mL, hiP, loP, out, c);
      }
    }
  } else if (ws_size >= baseB){
    hipLaunchKernelGGL(k_prep_all, dim3(BB*HH + HH*SS/ROWS), dim3(512), 0, stream,
                       values, temp, ln_w, ln_b, alpha, score_ln, hiP, loP, A_soft);
    hipLaunchKernelGGL((k_mfma_t<BB>), dim3(HH*16*BB), dim3(512), 0, stream,
                       hiP, loP, gamma, U, V, score_ln, A_soft, out, 0);
  } else {
    hipLaunchKernelGGL(k_score, dim3(BB*HH), dim3(512), 0, stream,
                       values, temp, ln_w, ln_b, score_ln);
    hipLaunchKernelGGL(k_main_lds, dim3(BB*HH*(SS/ROWS)), dim3(512), 0, stream,
                       values, alpha, gamma, U, V, score_ln, out);
  }
}

// Round 13
// 181.798 us; speedup vs baseline: 1.3215x; 1.3215x over previous
//
#include <hip/hip_runtime.h>
#include <math.h>

#define BB 16
#define HH 8
#define SS 512
#define FF 512
#define DD 64
#define RANKK 12
#define KTOP 51
#define ROWS 8

typedef __attribute__((ext_vector_type(8))) short bf16x8;
typedef __attribute__((ext_vector_type(4))) float f32x4;

// ---------- bf16 helpers (explicit RNE, deterministic) ----------
__device__ __forceinline__ unsigned short f2bf(float x){
  unsigned u = __float_as_uint(x);
  return (unsigned short)((u + 0x7FFFu + ((u>>16)&1u)) >> 16);
}
__device__ __forceinline__ float bf2f(unsigned short h){
  return __uint_as_float(((unsigned)h)<<16);
}

// monotonic float->uint order mapping (no NaNs in this problem)
__device__ __forceinline__ unsigned f2ord(float x){
  unsigned u = __float_as_uint(x);
  return (u & 0x80000000u) ? ~u : (u | 0x80000000u);
}

// One wave owns one row of 512 values (8 per lane, f = lane*8+j).
// Early exit when cnt==KTOP is EXACT (kept set identical).  (FROZEN)
__device__ __forceinline__ void topk_softmax8(float (&a)[8]){
  unsigned key[8];
#pragma unroll
  for (int j=0;j<8;++j) key[j] = f2ord(a[j]);
  unsigned T = 0u;
#pragma unroll
  for (int bit=31; bit>=0; --bit){
    unsigned Tp = T | (1u<<bit);
    int cnt = 0;
#pragma unroll
    for (int j=0;j<8;++j){
      unsigned long long bl = __ballot(key[j] >= Tp);
      cnt += __popcll(bl);
    }
    if (cnt >= KTOP) T = Tp;
    if (cnt == KTOP) break;            // wave-uniform exact early exit
  }
  float m = a[0];
#pragma unroll
  for (int j=1;j<8;++j) m = fmaxf(m, a[j]);
#pragma unroll
  for (int off=32; off>=1; off>>=1) m = fmaxf(m, __shfl_xor(m, off));
  float sum = 0.f;
#pragma unroll
  for (int j=0;j<8;++j){
    float e = (key[j] >= T) ? expf(a[j]-m) : 0.f;
    a[j] = e; sum += e;
  }
#pragma unroll
  for (int off=32; off>=1; off>>=1) sum += __shfl_xor(sum, off);
  float inv = 1.f/sum;
#pragma unroll
  for (int j=0;j<8;++j) a[j] *= inv;
}

// Two-row interleaved variant: ballot chains of two INDEPENDENT rows are
// interleaved (latency overlap); each row's T-trajectory, kept set, and fp
// op order are IDENTICAL to topk_softmax8 -> bit-identical results.
__device__ __forceinline__ void topk_softmax8_x2(float (&a)[8], float (&c)[8]){
  unsigned ka[8], kc[8];
#pragma unroll
  for (int j=0;j<8;++j){ ka[j] = f2ord(a[j]); kc[j] = f2ord(c[j]); }
  unsigned Ta = 0u, Tc = 0u;
  bool da = false, dc = false;
#pragma unroll
  for (int bit=31; bit>=0; --bit){
    const unsigned Tpa = Ta | (1u<<bit);
    const unsigned Tpc = Tc | (1u<<bit);
    int cnta = 0, cntc = 0;
#pragma unroll
    for (int j=0;j<8;++j){
      cnta += __popcll(__ballot(ka[j] >= Tpa));
      cntc += __popcll(__ballot(kc[j] >= Tpc));
    }
    if (!da){
      if (cnta >= KTOP) Ta = Tpa;
      if (cnta == KTOP) da = true;
    }
    if (!dc){
      if (cntc >= KTOP) Tc = Tpc;
      if (cntc == KTOP) dc = true;
    }
    if (da && dc) break;
  }
  // ---- finish row A (exact op order of topk_softmax8 tail) ----
  {
    float m = a[0];
#pragma unroll
    for (int j=1;j<8;++j) m = fmaxf(m, a[j]);
#pragma unroll
    for (int off=32; off>=1; off>>=1) m = fmaxf(m, __shfl_xor(m, off));
    float sum = 0.f;
#pragma unroll
    for (int j=0;j<8;++j){
      float e = (ka[j] >= Ta) ? expf(a[j]-m) : 0.f;
      a[j] = e; sum += e;
    }
#pragma unroll
    for (int off=32; off>=1; off>>=1) sum += __shfl_xor(sum, off);
    float inv = 1.f/sum;
#pragma unroll
    for (int j=0;j<8;++j) a[j] *= inv;
  }
  // ---- finish row C ----
  {
    float m = c[0];
#pragma unroll
    for (int j=1;j<8;++j) m = fmaxf(m, c[j]);
#pragma unroll
    for (int off=32; off>=1; off>>=1) m = fmaxf(m, __shfl_xor(m, off));
    float sum = 0.f;
#pragma unroll
    for (int j=0;j<8;++j){
      float e = (kc[j] >= Tc) ? expf(c[j]-m) : 0.f;
      c[j] = e; sum += e;
    }
#pragma unroll
    for (int off=32; off>=1; off>>=1) sum += __shfl_xor(sum, off);
    float inv = 1.f/sum;
#pragma unroll
    for (int j=0;j<8;++j) c[j] *= inv;
  }
}

// ---------------------------------------------------------------------------
// Fused prologue: blocks [0,128): transpose pass + score pass (verbatim);
// blocks [128,640): alpha body (verbatim). One launch.  (FROZEN bits)
// ---------------------------------------------------------------------------
__global__ __launch_bounds__(512) void k_prep_all(
    const float* __restrict__ values, const float* __restrict__ temp,
    const float* __restrict__ ln_w, const float* __restrict__ ln_b,
    const float* __restrict__ alpha, float* __restrict__ score_ln,
    unsigned short* __restrict__ hiP, unsigned short* __restrict__ loP,
    float* __restrict__ A_soft)
{
  const int tid = threadIdx.x, w = tid >> 6, lane = tid & 63;
  if (blockIdx.x >= BB*HH){
    const int row = (int)(blockIdx.x - BB*HH) * ROWS + w;
    const float SCALE = (float)(1.0/sqrt((double)FF));
    const float* ar = alpha + (size_t)row*FF + lane*8;
    float4 v0 = *(const float4*)ar;
    float4 v1 = *(const float4*)(ar+4);
    float a[8] = {v0.x*SCALE, v0.y*SCALE, v0.z*SCALE, v0.w*SCALE,
                  v1.x*SCALE, v1.y*SCALE, v1.z*SCALE, v1.w*SCALE};
    topk_softmax8(a);
    float* orow = A_soft + (size_t)row*FF + lane*8;
    *(float4*)orow     = make_float4(a[0],a[1],a[2],a[3]);
    *(float4*)(orow+4) = make_float4(a[4],a[5],a[6],a[7]);
    return;
  }
  __shared__ float tile[64][65];
  __shared__ float s_e[FF];
  __shared__ float ps[8], ps2[8];
  const int b = blockIdx.x / HH, h = blockIdx.x % HH;
  const float* vb = values + ((size_t)b*FF*HH + h)*DD;

  for (int c=0;c<8;++c){
#pragma unroll
    for (int p=0;p<8;++p){
      const int fi = p*8 + w;
      const int f  = c*64 + fi;
      tile[fi][lane] = vb[(size_t)f*HH*DD + lane];
    }
    __syncthreads();
    {
      const int d  = w*8 + (lane>>3);
      const int fj = (lane&7)*8;
      unsigned short hs[8], ls[8];
#pragma unroll
      for (int j=0;j<8;++j){
        float x = tile[fj+j][d];
        hs[j] = f2bf(x);
        ls[j] = f2bf(x - bf2f(hs[j]));
      }
      uint4 H4, L4;
      H4.x=(unsigned)hs[0]|((unsigned)hs[1]<<16); H4.y=(unsigned)hs[2]|((unsigned)hs[3]<<16);
      H4.z=(unsigned)hs[4]|((unsigned)hs[5]<<16); H4.w=(unsigned)hs[6]|((unsigned)hs[7]<<16);
      L4.x=(unsigned)ls[0]|((unsigned)ls[1]<<16); L4.y=(unsigned)ls[2]|((unsigned)ls[3]<<16);
      L4.z=(unsigned)ls[4]|((unsigned)ls[5]<<16); L4.w=(unsigned)ls[6]|((unsigned)ls[7]<<16);
      const size_t base = ((size_t)blockIdx.x*DD + d)*FF + c*64 + fj;
      *(uint4*)(hiP + base) = H4;
      *(uint4*)(loP + base) = L4;
    }
    __syncthreads();
  }

  for (int i=0;i<FF/8;++i){
    int f = w*(FF/8) + i;
    float v = vb[(size_t)f*HH*DD + lane];
    float e = v*v;
#pragma unroll
    for (int off=32; off>=1; off>>=1) e += __shfl_xor(e, off);
    if (lane==0) s_e[f] = e * (1.0f/DD);
  }
  __syncthreads();
  float e = s_e[tid];
  float se = e, se2 = e*e;
#pragma unroll
  for (int off=32; off>=1; off>>=1){ se += __shfl_xor(se, off); se2 += __shfl_xor(se2, off); }
  if (lane==0){ ps[w]=se; ps2[w]=se2; }
  __syncthreads();
  float S1=0.f, S2=0.f;
#pragma unroll
  for (int g=0; g<8; ++g){ S1 += ps[g]; S2 += ps2[g]; }
  float meanE = S1 * (1.0f/FF);
  float rms = fmaxf(sqrtf(meanE), 1e-6f);
  float t = temp[h];
  float gain = (t > 20.f) ? t : log1pf(expf(t));
  float c = gain / rms;
  float mu = c * meanE;
  float var = c*c*(S2*(1.0f/FF) - meanE*meanE);
  float inv = rsqrtf(var + 1e-5f);
  score_ln[(size_t)blockIdx.x*FF + tid] = (c*e - mu)*inv*ln_w[tid] + ln_b[tid];
}

// Kernel: score only (deep-fallback path)
__global__ __launch_bounds__(512) void k_score(const float* __restrict__ values,
    const float* __restrict__ temp, const float* __restrict__ ln_w,
    const float* __restrict__ ln_b, float* __restrict__ score_ln)
{
  const int b = blockIdx.x / HH, h = blockIdx.x % HH;
  const int tid = threadIdx.x, w = tid >> 6, lane = tid & 63;
  __shared__ float s_e[FF];
  __shared__ float ps[8], ps2[8];
  const float* vb = values + ((size_t)b*FF*HH + h)*DD;
  for (int i=0;i<FF/8;++i){
    int f = w*(FF/8) + i;
    float v = vb[(size_t)f*HH*DD + lane];
    float e = v*v;
#pragma unroll
    for (int off=32; off>=1; off>>=1) e += __shfl_xor(e, off);
    if (lane==0) s_e[f] = e * (1.0f/DD);
  }
  __syncthreads();
  float e = s_e[tid];
  float se = e, se2 = e*e;
#pragma unroll
  for (int off=32; off>=1; off>>=1){ se += __shfl_xor(se, off); se2 += __shfl_xor(se2, off); }
  if (lane==0){ ps[w]=se; ps2[w]=se2; }
  __syncthreads();
  float S1=0.f, S2=0.f;
#pragma unroll
  for (int g=0; g<8; ++g){ S1 += ps[g]; S2 += ps2[g]; }
  float meanE = S1 * (1.0f/FF);
  float rms = fmaxf(sqrtf(meanE), 1e-6f);
  float t = temp[h];
  float gain = (t > 20.f) ? t : log1pf(expf(t));
  float c = gain / rms;
  float mu = c * meanE;
  float var = c*c*(S2*(1.0f/FF) - meanE*meanE);
  float inv = rsqrtf(var + 1e-5f);
  score_ln[(size_t)blockIdx.x*FF + tid] = (c*e - mu)*inv*ln_w[tid] + ln_b[tid];
}

// ---------- phase-1 helper, 2 rows interleaved (per-row bits FROZEN) ------
__device__ __forceinline__ void build_mix_row2(int bh, int h, int sA, int sB,
    int lane, const float* __restrict__ score_ln, const float* __restrict__ gamma,
    const float* __restrict__ U, const float* __restrict__ V,
    const float* __restrict__ A_soft,
    float4& mA0, float4& mA1, float4& mB0, float4& mB1)
{
  const int f0 = lane*8;
  const float* sr = score_ln + (size_t)bh*FF + f0;
  float4 sv0 = *(const float4*)sr;
  float4 sv1 = *(const float4*)(sr+4);
  const float gA = gamma[h*SS + sA];
  const float gB = gamma[h*SS + sB];
  float dlA[8] = {sv0.x+gA, sv0.y+gA, sv0.z+gA, sv0.w+gA,
                  sv1.x+gA, sv1.y+gA, sv1.z+gA, sv1.w+gA};
  float dlB[8] = {sv0.x+gB, sv0.y+gB, sv0.z+gB, sv0.w+gB,
                  sv1.x+gB, sv1.y+gB, sv1.z+gB, sv1.w+gB};
  const float* UrA = U + ((size_t)h*SS + sA)*RANKK;
  const float* UrB = U + ((size_t)h*SS + sB)*RANKK;
  const float* Vh = V + (size_t)h*RANKK*FF + f0;
#pragma unroll
  for (int r=0;r<RANKK;++r){
    float4 b0 = *(const float4*)(Vh + r*FF);
    float4 b1 = *(const float4*)(Vh + r*FF + 4);
    float uA = UrA[r];
    dlA[0] += uA*b0.x; dlA[1] += uA*b0.y; dlA[2] += uA*b0.z; dlA[3] += uA*b0.w;
    dlA[4] += uA*b1.x; dlA[5] += uA*b1.y; dlA[6] += uA*b1.z; dlA[7] += uA*b1.w;
    float uB = UrB[r];
    dlB[0] += uB*b0.x; dlB[1] += uB*b0.y; dlB[2] += uB*b0.z; dlB[3] += uB*b0.w;
    dlB[4] += uB*b1.x; dlB[5] += uB*b1.y; dlB[6] += uB*b1.z; dlB[7] += uB*b1.w;
  }
  topk_softmax8_x2(dlA, dlB);
  const float* arA = A_soft + ((size_t)h*SS + sA)*FF + f0;
  float4 aA0 = *(const float4*)arA;
  float4 aA1 = *(const float4*)(arA+4);
  mA0 = make_float4(dlA[0]+aA0.x, dlA[1]+aA0.y, dlA[2]+aA0.z, dlA[3]+aA0.w);
  mA1 = make_float4(dlA[4]+aA1.x, dlA[5]+aA1.y, dlA[6]+aA1.z, dlA[7]+aA1.w);
  const float* arB = A_soft + ((size_t)h*SS + sB)*FF + f0;
  float4 aB0 = *(const float4*)arB;
  float4 aB1 = *(const float4*)(arB+4);
  mB0 = make_float4(dlB[0]+aB0.x, dlB[1]+aB0.y, dlB[2]+aB0.z, dlB[3]+aB0.w);
  mB1 = make_float4(dlB[4]+aB1.x, dlB[5]+aB1.y, dlB[6]+aB1.z, dlB[7]+aB1.w);
}

// single-row helper (deep fallback only)
__device__ __forceinline__ void build_mix_row(int bh, int h, int s, int lane,
    const float* __restrict__ score_ln, const float* __restrict__ gamma,
    const float* __restrict__ U, const float* __restrict__ V,
    const float* __restrict__ A_soft, float4& m0, float4& m1)
{
  const int f0 = lane*8;
  const float* sr = score_ln + (size_t)bh*FF + f0;
  float4 sv0 = *(const float4*)sr;
  float4 sv1 = *(const float4*)(sr+4);
  const float g = gamma[h*SS + s];
  float dl[8] = {sv0.x+g, sv0.y+g, sv0.z+g, sv0.w+g,
                 sv1.x+g, sv1.y+g, sv1.z+g, sv1.w+g};
  const float* Ur = U + ((size_t)h*SS + s)*RANKK;
  const float* Vh = V + (size_t)h*RANKK*FF + f0;
#pragma unroll
  for (int r=0;r<RANKK;++r){
    float u = Ur[r];
    float4 b0 = *(const float4*)(Vh + r*FF);
    float4 b1 = *(const float4*)(Vh + r*FF + 4);
    dl[0] += u*b0.x; dl[1] += u*b0.y; dl[2] += u*b0.z; dl[3] += u*b0.w;
    dl[4] += u*b1.x; dl[5] += u*b1.y; dl[6] += u*b1.z; dl[7] += u*b1.w;
  }
  topk_softmax8(dl);
  const float* arow = A_soft + ((size_t)h*SS + s)*FF + f0;
  float4 a0 = *(const float4*)arow;
  float4 a1 = *(const float4*)(arow+4);
  m0 = make_float4(dl[0]+a0.x, dl[1]+a0.y, dl[2]+a0.z, dl[3]+a0.w);
  m1 = make_float4(dl[4]+a1.x, dl[5]+a1.y, dl[6]+a1.z, dl[7]+a1.w);
}

__device__ __forceinline__ void gload16(const void* g, void* l){
  __builtin_amdgcn_global_load_lds(
      (const __attribute__((address_space(1))) unsigned int*)g,
      (__attribute__((address_space(3))) unsigned int*)l, 16, 0, 0);
}

// ---------- MFMA main (r8 structure): 32s x 64d, staged B, 1-barrier loop ----
template<int NB>
__global__ __launch_bounds__(512, 4) void k_mfma_t(
    const unsigned short* __restrict__ hiP, const unsigned short* __restrict__ loP,
    const float* __restrict__ gamma, const float* __restrict__ U,
    const float* __restrict__ V, const float* __restrict__ score_ln,
    const float* __restrict__ A_soft, float* __restrict__ out, int b0)
{
  __shared__ __align__(16) unsigned char Abuf[65536];   // A hi [0,32K), lo [32K,64K)
  __shared__ __align__(16) unsigned char Bbuf[2][8192]; // B chunk dbuf
  const int nwg = HH*NB*16;
  const int bid = (blockIdx.x & 7)*(nwg/8) + (blockIdx.x >> 3); // XCD chunk swizzle
  const int grp  = bid >> 4;           // h*NB + bloc
  const int sblk = bid & 15;
  const int h    = grp / NB;
  const int bloc = grp % NB;
  const int b    = b0 + bloc;
  const int s0   = sblk*32;
  const int bh   = b*HH + h;
  const int tid = threadIdx.x, w = tid>>6, lane = tid&63;

  // ---- staging source decode (rule 21: linear LDS dest, pre-swizzled src) ----
  const size_t pbBase = (size_t)(bloc*HH + h)*DD*FF;
  const int dw  = tid >> 3;            // d row 0..63
  const int s8p = tid & 7;             // swizzled 16B slot in 128B row
  const int s8  = s8p ^ (dw & 7);      // unswizzled slot: plane*4 + seg
  const unsigned short* sp = ((s8 & 4) ? loP : hiP)
                             + pbBase + (size_t)dw*FF + (size_t)(s8 & 3)*8;
  gload16(sp, &Bbuf[0][(unsigned)w<<10]);   // stage(0) hides under phase-1

  // ---- phase 1: wave w builds mix rows w*4..w*4+3 as 2 interleaved pairs ----
#pragma unroll
  for (int i=0;i<2;++i){
    const int slA = w*4 + i*2;
    const int slB = slA + 1;
    float4 mA0, mA1, mB0, mB1;
    build_mix_row2(bh, h, s0+slA, s0+slB, lane, score_ln, gamma, U, V, A_soft,
                   mA0, mA1, mB0, mB1);
    float xsA[8] = {mA0.x,mA0.y,mA0.z,mA0.w,mA1.x,mA1.y,mA1.z,mA1.w};
    float xsB[8] = {mB0.x,mB0.y,mB0.z,mB0.w,mB1.x,mB1.y,mB1.z,mB1.w};
    unsigned short hvA[8], lvA[8], hvB[8], lvB[8];
#pragma unroll
    for (int j=0;j<8;++j){
      hvA[j] = f2bf(xsA[j]);  lvA[j] = f2bf(xsA[j] - bf2f(hvA[j]));
      hvB[j] = f2bf(xsB[j]);  lvB[j] = f2bf(xsB[j] - bf2f(hvB[j]));
    }
    uint4 H4, L4;
    H4.x=(unsigned)hvA[0]|((unsigned)hvA[1]<<16); H4.y=(unsigned)hvA[2]|((unsigned)hvA[3]<<16);
    H4.z=(unsigned)hvA[4]|((unsigned)hvA[5]<<16); H4.w=(unsigned)hvA[6]|((unsigned)hvA[7]<<16);
    L4.x=(unsigned)lvA[0]|((unsigned)lvA[1]<<16); L4.y=(unsigned)lvA[2]|((unsigned)lvA[3]<<16);
    L4.z=(unsigned)lvA[4]|((unsigned)lvA[5]<<16); L4.w=(unsigned)lvA[6]|((unsigned)lvA[7]<<16);
    const unsigned bytA = (unsigned)(slA*1024 + lane*16) ^ (unsigned)((slA&15)<<4);
    *(uint4*)(Abuf + bytA)          = H4;
    *(uint4*)(Abuf + 32768 + bytA)  = L4;
    H4.x=(unsigned)hvB[0]|((unsigned)hvB[1]<<16); H4.y=(unsigned)hvB[2]|((unsigned)hvB[3]<<16);
    H4.z=(unsigned)hvB[4]|((unsigned)hvB[5]<<16); H4.w=(unsigned)hvB[6]|((unsigned)hvB[7]<<16);
    L4.x=(unsigned)lvB[0]|((unsigned)lvB[1]<<16); L4.y=(unsigned)lvB[2]|((unsigned)lvB[3]<<16);
    L4.z=(unsigned)lvB[4]|((unsigned)lvB[5]<<16); L4.w=(unsigned)lvB[6]|((unsigned)lvB[7]<<16);
    const unsigned bytB = (unsigned)(slB*1024 + lane*16) ^ (unsigned)((slB&15)<<4);
    *(uint4*)(Abuf + bytB)          = H4;
    *(uint4*)(Abuf + 32768 + bytB)  = L4;
  }
  __syncthreads();   // drains everything incl. stage(0)

  // ---- phase 2: wave (stile,ntile) computes 16s x 16d, K=512 ----
  const int stile = w>>2, ntile = w&3;
  const int srow  = stile*16 + (lane&15);
  const unsigned sw = (unsigned)((lane&15)<<4);
  const unsigned a0off = (unsigned)(srow*1024 + ((lane>>4)*16));
  const int d    = ntile*16 + (lane&15);
  const int sgr  = lane>>4;
  const unsigned offH = (unsigned)(d*128 + ((sgr    ) ^ (d&7))*16);
  const unsigned offL = (unsigned)(d*128 + ((sgr + 4) ^ (d&7))*16);

  f32x4 acc0 = {0.f,0.f,0.f,0.f};
  f32x4 acc1 = {0.f,0.f,0.f,0.f};

#pragma unroll
  for (int t=0;t<16;++t){
    if (t > 0){
      asm volatile("s_waitcnt vmcnt(0) lgkmcnt(0)" ::: "memory");
      __builtin_amdgcn_s_barrier();
    }
    if (t < 15)
      gload16(sp + (size_t)(t+1)*32, &Bbuf[(t+1)&1][(unsigned)w<<10]);
    const unsigned ax = (a0off + (unsigned)(t*64)) ^ sw;
    bf16x8 ah = *(const bf16x8*)(Abuf + ax);
    bf16x8 al = *(const bf16x8*)(Abuf + 32768 + ax);
    const unsigned char* bb = Bbuf[t&1];
    bf16x8 bhv = *(const bf16x8*)(bb + offH);
    bf16x8 blv = *(const bf16x8*)(bb + offL);
    __builtin_amdgcn_s_setprio(1);
    acc0 = __builtin_amdgcn_mfma_f32_16x16x32_bf16(ah, bhv, acc0, 0, 0, 0);
    acc1 = __builtin_amdgcn_mfma_f32_16x16x32_bf16(al, bhv, acc1, 0, 0, 0);
    acc1 = __builtin_amdgcn_mfma_f32_16x16x32_bf16(ah, blv, acc1, 0, 0, 0);
    __builtin_amdgcn_s_setprio(0);
  }

  // ---- epilogue: C/D map col=lane&15 (n=d), row=(lane>>4)*4+reg (m=s) ----
  const int m0r = stile*16 + (lane>>4)*4;
#pragma unroll
  for (int r=0;r<4;++r){
    const int s = s0 + m0r + r;
    __builtin_nontemporal_store(acc0[r] + acc1[r],
        &out[(((size_t)b*SS + s)*HH + h)*DD + d]);
  }
}

// ---------- deep fallback: r1 LDS-broadcast kernel ----------
__global__ __launch_bounds__(512) void k_main_lds(const float* __restrict__ values,
    const float* __restrict__ alpha, const float* __restrict__ gamma,
    const float* __restrict__ U, const float* __restrict__ V,
    const float* __restrict__ score_ln, float* __restrict__ out)
{
  const int nwg = BB*HH*(SS/ROWS);
  const int bid = (blockIdx.x & 7)*(nwg/8) + (blockIdx.x >> 3);
  const int blocksPerBH = SS / ROWS;
  const int bh = bid / blocksPerBH;
  const int s0 = (bid % blocksPerBH) * ROWS;
  const int b = bh / HH, h = bh % HH;
  const int tid = threadIdx.x, w = tid >> 6, lane = tid & 63;
  __shared__ float smix[ROWS][FF];

  {
    const int s = s0 + w;
    const int f0 = lane*8;
    const float* sr = score_ln + (size_t)bh*FF + f0;
    float4 sv0 = *(const float4*)sr;
    float4 sv1 = *(const float4*)(sr+4);
    const float g = gamma[h*SS + s];
    float dl[8] = {sv0.x+g, sv0.y+g, sv0.z+g, sv0.w+g,
                   sv1.x+g, sv1.y+g, sv1.z+g, sv1.w+g};
    const float* Ur = U + ((size_t)h*SS + s)*RANKK;
    const float* Vh = V + (size_t)h*RANKK*FF + f0;
#pragma unroll
    for (int r=0;r<RANKK;++r){
      float u = Ur[r];
      float4 b0 = *(const float4*)(Vh + r*FF);
      float4 b1 = *(const float4*)(Vh + r*FF + 4);
      dl[0] += u*b0.x; dl[1] += u*b0.y; dl[2] += u*b0.z; dl[3] += u*b0.w;
      dl[4] += u*b1.x; dl[5] += u*b1.y; dl[6] += u*b1.z; dl[7] += u*b1.w;
    }
    topk_softmax8(dl);
    const float SCALE = (float)(1.0/sqrt((double)FF));
    const float* arow = alpha + ((size_t)h*SS + s)*FF + f0;
    float4 a0 = *(const float4*)arow;
    float4 a1 = *(const float4*)(arow+4);
    float ap[8] = {a0.x*SCALE, a0.y*SCALE, a0.z*SCALE, a0.w*SCALE,
                   a1.x*SCALE, a1.y*SCALE, a1.z*SCALE, a1.w*SCALE};
    topk_softmax8(ap);
    float4 m0 = make_float4(dl[0]+ap[0], dl[1]+ap[1], dl[2]+ap[2], dl[3]+ap[3]);
    float4 m1 = make_float4(dl[4]+ap[4], dl[5]+ap[5], dl[6]+ap[6], dl[7]+ap[7]);
    *(float4*)&smix[w][f0]   = m0;
    *(float4*)&smix[w][f0+4] = m1;
  }
  __syncthreads();

  float acc[ROWS] = {0,0,0,0,0,0,0,0};
  {
    const float* vp = values + (size_t)b*FF*HH*DD + (size_t)h*DD + lane;
#pragma unroll
    for (int i=0;i<16;++i){
      const int f0 = w*64 + i*4;
      float x0 = vp[(size_t)(f0+0)*HH*DD];
      float x1 = vp[(size_t)(f0+1)*HH*DD];
      float x2 = vp[(size_t)(f0+2)*HH*DD];
      float x3 = vp[(size_t)(f0+3)*HH*DD];
#pragma unroll
      for (int r=0;r<ROWS;++r){
        float4 m = *(const float4*)&smix[r][f0];
        acc[r] += m.x*x0 + m.y*x1 + m.z*x2 + m.w*x3;
      }
    }
  }
  __syncthreads();

  float* red = &smix[0][0];
#pragma unroll
  for (int r=0;r<ROWS;++r) red[(w*ROWS + r)*64 + lane] = acc[r];
  __syncthreads();
  {
    const int r = w, dd = lane;
    float sum = 0.f;
#pragma unroll
    for (int g=0; g<8; ++g) sum += red[(g*ROWS + r)*64 + dd];
    out[(((size_t)b*SS + s0 + r)*HH + h)*DD + dd] = sum;
  }
}

extern "C" void kernel_launch(void* const* d_in, const int* in_sizes, int n_in,
                              void* d_out, int out_size, void* d_ws, size_t ws_size,
                              hipStream_t stream) {
  const float* values = (const float*)d_in[0];
  const float* alpha  = (const float*)d_in[1];
  const float* temp   = (const float*)d_in[2];
  const float* gamma  = (const float*)d_in[3];
  const float* U      = (const float*)d_in[4];
  const float* V      = (const float*)d_in[5];
  const float* ln_w   = (const float*)d_in[6];
  const float* ln_b   = (const float*)d_in[7];
  float* out = (float*)d_out;
  float* ws  = (float*)d_ws;

  const size_t scoreN = (size_t)BB*HH*FF;             // 65,536 floats
  const size_t alphaN = (size_t)HH*SS*FF;             // 2,097,152 floats
  const size_t planeN = (size_t)BB*HH*DD*FF;          // 4,194,304 ushorts/plane

  float* score_ln = ws;
  float* A_soft   = ws + scoreN;
  unsigned short* hiP = (unsigned short*)(ws + scoreN + alphaN);
  unsigned short* loP = hiP + planeN;

  const size_t needFull = scoreN*4 + alphaN*4 + 2*planeN*2;   // 25.4 MB (proven)

  if (ws_size >= needFull){
    hipLaunchKernelGGL(k_prep_all, dim3(BB*HH + HH*SS/ROWS), dim3(512), 0, stream,
                       values, temp, ln_w, ln_b, alpha, score_ln, hiP, loP, A_soft);
    hipLaunchKernelGGL((k_mfma_t<BB>), dim3(HH*16*BB), dim3(512), 0, stream,
                       hiP, loP, gamma, U, V, score_ln, A_soft, out, 0);
  } else {
    hipLaunchKernelGGL(k_score, dim3(BB*HH), dim3(512), 0, stream,
                       values, temp, ln_w, ln_b, score_ln);
    hipLaunchKernelGGL(k_main_lds, dim3(BB*HH*(SS/ROWS)), dim3(512), 0, stream,
                       values, alpha, gamma, U, V, score_ln, out);
  }
}

// Round 14
// 176.593 us; speedup vs baseline: 1.3605x; 1.0295x over previous
//
#include <hip/hip_runtime.h>
#include <math.h>

#define BB 16
#define HH 8
#define SS 512
#define FF 512
#define DD 64
#define RANKK 12
#define KTOP 51
#define ROWS 8

typedef __attribute__((ext_vector_type(8))) short bf16x8;
typedef __attribute__((ext_vector_type(4))) float f32x4;

// ---------- bf16 helpers (explicit RNE, deterministic) ----------
__device__ __forceinline__ unsigned short f2bf(float x){
  unsigned u = __float_as_uint(x);
  return (unsigned short)((u + 0x7FFFu + ((u>>16)&1u)) >> 16);
}
__device__ __forceinline__ float bf2f(unsigned short h){
  return __uint_as_float(((unsigned)h)<<16);
}

// monotonic float->uint order mapping (no NaNs in this problem)
__device__ __forceinline__ unsigned f2ord(float x){
  unsigned u = __float_as_uint(x);
  return (u & 0x80000000u) ? ~u : (u | 0x80000000u);
}

// One wave owns one row of 512 values (8 per lane, f = lane*8+j).
// Early exit when cnt==KTOP is EXACT (kept set identical).  (FROZEN)
__device__ __forceinline__ void topk_softmax8(float (&a)[8]){
  unsigned key[8];
#pragma unroll
  for (int j=0;j<8;++j) key[j] = f2ord(a[j]);
  unsigned T = 0u;
#pragma unroll
  for (int bit=31; bit>=0; --bit){
    unsigned Tp = T | (1u<<bit);
    int cnt = 0;
#pragma unroll
    for (int j=0;j<8;++j){
      unsigned long long bl = __ballot(key[j] >= Tp);
      cnt += __popcll(bl);
    }
    if (cnt >= KTOP) T = Tp;
    if (cnt == KTOP) break;            // wave-uniform exact early exit
  }
  float m = a[0];
#pragma unroll
  for (int j=1;j<8;++j) m = fmaxf(m, a[j]);
#pragma unroll
  for (int off=32; off>=1; off>>=1) m = fmaxf(m, __shfl_xor(m, off));
  float sum = 0.f;
#pragma unroll
  for (int j=0;j<8;++j){
    float e = (key[j] >= T) ? expf(a[j]-m) : 0.f;
    a[j] = e; sum += e;
  }
#pragma unroll
  for (int off=32; off>=1; off>>=1) sum += __shfl_xor(sum, off);
  float inv = 1.f/sum;
#pragma unroll
  for (int j=0;j<8;++j) a[j] *= inv;
}

// ---------------------------------------------------------------------------
// Fused prologue: blocks [0,128): transpose pass WITH in-register energy
// (score's e computed from the SAME loaded v, identical op chain -> identical
// bits) + LN epilogue; blocks [128,640): alpha body (verbatim). One launch.
// ---------------------------------------------------------------------------
__global__ __launch_bounds__(512) void k_prep_all(
    const float* __restrict__ values, const float* __restrict__ temp,
    const float* __restrict__ ln_w, const float* __restrict__ ln_b,
    const float* __restrict__ alpha, float* __restrict__ score_ln,
    unsigned short* __restrict__ hiP, unsigned short* __restrict__ loP,
    float* __restrict__ A_soft)
{
  const int tid = threadIdx.x, w = tid >> 6, lane = tid & 63;
  if (blockIdx.x >= BB*HH){
    const int row = (int)(blockIdx.x - BB*HH) * ROWS + w;
    const float SCALE = (float)(1.0/sqrt((double)FF));
    const float* ar = alpha + (size_t)row*FF + lane*8;
    float4 v0 = *(const float4*)ar;
    float4 v1 = *(const float4*)(ar+4);
    float a[8] = {v0.x*SCALE, v0.y*SCALE, v0.z*SCALE, v0.w*SCALE,
                  v1.x*SCALE, v1.y*SCALE, v1.z*SCALE, v1.w*SCALE};
    topk_softmax8(a);
    float* orow = A_soft + (size_t)row*FF + lane*8;
    *(float4*)orow     = make_float4(a[0],a[1],a[2],a[3]);
    *(float4*)(orow+4) = make_float4(a[4],a[5],a[6],a[7]);
    return;
  }
  __shared__ float tile[64][65];
  __shared__ float s_e[FF];
  __shared__ float ps[8], ps2[8];
  const int b = blockIdx.x / HH, h = blockIdx.x % HH;
  const float* vb = values + ((size_t)b*FF*HH + h)*DD;

  // ---- transpose pass + in-register energy ----
  for (int c=0;c<8;++c){
#pragma unroll
    for (int p=0;p<8;++p){
      const int fi = p*8 + w;
      const int f  = c*64 + fi;
      float v = vb[(size_t)f*HH*DD + lane];
      tile[fi][lane] = v;
      float e = v*v;
#pragma unroll
      for (int off=32; off>=1; off>>=1) e += __shfl_xor(e, off);
      if (lane==0) s_e[f] = e * (1.0f/DD);
    }
    __syncthreads();
    {
      const int d  = w*8 + (lane>>3);
      const int fj = (lane&7)*8;
      unsigned short hs[8], ls[8];
#pragma unroll
      for (int j=0;j<8;++j){
        float x = tile[fj+j][d];
        hs[j] = f2bf(x);
        ls[j] = f2bf(x - bf2f(hs[j]));
      }
      uint4 H4, L4;
      H4.x=(unsigned)hs[0]|((unsigned)hs[1]<<16); H4.y=(unsigned)hs[2]|((unsigned)hs[3]<<16);
      H4.z=(unsigned)hs[4]|((unsigned)hs[5]<<16); H4.w=(unsigned)hs[6]|((unsigned)hs[7]<<16);
      L4.x=(unsigned)ls[0]|((unsigned)ls[1]<<16); L4.y=(unsigned)ls[2]|((unsigned)ls[3]<<16);
      L4.z=(unsigned)ls[4]|((unsigned)ls[5]<<16); L4.w=(unsigned)ls[6]|((unsigned)ls[7]<<16);
      const size_t base = ((size_t)blockIdx.x*DD + d)*FF + c*64 + fj;
      *(uint4*)(hiP + base) = H4;
      *(uint4*)(loP + base) = L4;
    }
    __syncthreads();
  }

  // ---- LN epilogue (verbatim) ----
  float e = s_e[tid];
  float se = e, se2 = e*e;
#pragma unroll
  for (int off=32; off>=1; off>>=1){ se += __shfl_xor(se, off); se2 += __shfl_xor(se2, off); }
  if (lane==0){ ps[w]=se; ps2[w]=se2; }
  __syncthreads();
  float S1=0.f, S2=0.f;
#pragma unroll
  for (int g=0; g<8; ++g){ S1 += ps[g]; S2 += ps2[g]; }
  float meanE = S1 * (1.0f/FF);
  float rms = fmaxf(sqrtf(meanE), 1e-6f);
  float t = temp[h];
  float gain = (t > 20.f) ? t : log1pf(expf(t));
  float c = gain / rms;
  float mu = c * meanE;
  float var = c*c*(S2*(1.0f/FF) - meanE*meanE);
  float inv = rsqrtf(var + 1e-5f);
  score_ln[(size_t)blockIdx.x*FF + tid] = (c*e - mu)*inv*ln_w[tid] + ln_b[tid];
}

// Kernel: score only (deep-fallback path)
__global__ __launch_bounds__(512) void k_score(const float* __restrict__ values,
    const float* __restrict__ temp, const float* __restrict__ ln_w,
    const float* __restrict__ ln_b, float* __restrict__ score_ln)
{
  const int b = blockIdx.x / HH, h = blockIdx.x % HH;
  const int tid = threadIdx.x, w = tid >> 6, lane = tid & 63;
  __shared__ float s_e[FF];
  __shared__ float ps[8], ps2[8];
  const float* vb = values + ((size_t)b*FF*HH + h)*DD;
  for (int i=0;i<FF/8;++i){
    int f = w*(FF/8) + i;
    float v = vb[(size_t)f*HH*DD + lane];
    float e = v*v;
#pragma unroll
    for (int off=32; off>=1; off>>=1) e += __shfl_xor(e, off);
    if (lane==0) s_e[f] = e * (1.0f/DD);
  }
  __syncthreads();
  float e = s_e[tid];
  float se = e, se2 = e*e;
#pragma unroll
  for (int off=32; off>=1; off>>=1){ se += __shfl_xor(se, off); se2 += __shfl_xor(se2, off); }
  if (lane==0){ ps[w]=se; ps2[w]=se2; }
  __syncthreads();
  float S1=0.f, S2=0.f;
#pragma unroll
  for (int g=0; g<8; ++g){ S1 += ps[g]; S2 += ps2[g]; }
  float meanE = S1 * (1.0f/FF);
  float rms = fmaxf(sqrtf(meanE), 1e-6f);
  float t = temp[h];
  float gain = (t > 20.f) ? t : log1pf(expf(t));
  float c = gain / rms;
  float mu = c * meanE;
  float var = c*c*(S2*(1.0f/FF) - meanE*meanE);
  float inv = rsqrtf(var + 1e-5f);
  score_ln[(size_t)blockIdx.x*FF + tid] = (c*e - mu)*inv*ln_w[tid] + ln_b[tid];
}

// ---------- phase-1 helper (FROZEN — validated bits) ----------
__device__ __forceinline__ void build_mix_row(int bh, int h, int s, int lane,
    const float* __restrict__ score_ln, const float* __restrict__ gamma,
    const float* __restrict__ U, const float* __restrict__ V,
    const float* __restrict__ A_soft, float4& m0, float4& m1)
{
  const int f0 = lane*8;
  const float* sr = score_ln + (size_t)bh*FF + f0;
  float4 sv0 = *(const float4*)sr;
  float4 sv1 = *(const float4*)(sr+4);
  const float g = gamma[h*SS + s];
  float dl[8] = {sv0.x+g, sv0.y+g, sv0.z+g, sv0.w+g,
                 sv1.x+g, sv1.y+g, sv1.z+g, sv1.w+g};
  const float* Ur = U + ((size_t)h*SS + s)*RANKK;
  const float* Vh = V + (size_t)h*RANKK*FF + f0;
#pragma unroll
  for (int r=0;r<RANKK;++r){
    float u = Ur[r];
    float4 b0 = *(const float4*)(Vh + r*FF);
    float4 b1 = *(const float4*)(Vh + r*FF + 4);
    dl[0] += u*b0.x; dl[1] += u*b0.y; dl[2] += u*b0.z; dl[3] += u*b0.w;
    dl[4] += u*b1.x; dl[5] += u*b1.y; dl[6] += u*b1.z; dl[7] += u*b1.w;
  }
  topk_softmax8(dl);
  const float* arow = A_soft + ((size_t)h*SS + s)*FF + f0;
  float4 a0 = *(const float4*)arow;
  float4 a1 = *(const float4*)(arow+4);
  m0 = make_float4(dl[0]+a0.x, dl[1]+a0.y, dl[2]+a0.z, dl[3]+a0.w);
  m1 = make_float4(dl[4]+a1.x, dl[5]+a1.y, dl[6]+a1.z, dl[7]+a1.w);
}

__device__ __forceinline__ void gload16(const void* g, void* l){
  __builtin_amdgcn_global_load_lds(
      (const __attribute__((address_space(1))) unsigned int*)g,
      (__attribute__((address_space(3))) unsigned int*)l, 16, 0, 0);
}

// ---------- MFMA main (r8 structure): 32s x 64d, staged B, 1-barrier loop ----
// Epilogue: f32 tile staged in Abuf (free after K-loop) -> full-128B-line
// float4 stores (kills the NT partial-line RMW: WRITE 135MB -> ~70MB).
template<int NB>
__global__ __launch_bounds__(512, 4) void k_mfma_t(
    const unsigned short* __restrict__ hiP, const unsigned short* __restrict__ loP,
    const float* __restrict__ gamma, const float* __restrict__ U,
    const float* __restrict__ V, const float* __restrict__ score_ln,
    const float* __restrict__ A_soft, float* __restrict__ out, int b0)
{
  __shared__ __align__(16) unsigned char Abuf[65536];   // A hi [0,32K), lo [32K,64K)
  __shared__ __align__(16) unsigned char Bbuf[2][8192]; // B chunk dbuf
  const int nwg = HH*NB*16;
  const int bid = (blockIdx.x & 7)*(nwg/8) + (blockIdx.x >> 3); // XCD chunk swizzle
  const int grp  = bid >> 4;           // h*NB + bloc
  const int sblk = bid & 15;
  const int h    = grp / NB;
  const int bloc = grp % NB;
  const int b    = b0 + bloc;
  const int s0   = sblk*32;
  const int bh   = b*HH + h;
  const int tid = threadIdx.x, w = tid>>6, lane = tid&63;

  // ---- staging source decode (rule 21: linear LDS dest, pre-swizzled src) ----
  const size_t pbBase = (size_t)(bloc*HH + h)*DD*FF;
  const int dw  = tid >> 3;            // d row 0..63
  const int s8p = tid & 7;             // swizzled 16B slot in 128B row
  const int s8  = s8p ^ (dw & 7);      // unswizzled slot: plane*4 + seg
  const unsigned short* sp = ((s8 & 4) ? loP : hiP)
                             + pbBase + (size_t)dw*FF + (size_t)(s8 & 3)*8;
  gload16(sp, &Bbuf[0][(unsigned)w<<10]);   // stage(0) hides under phase-1

  // ---- phase 1: wave w builds mix rows sl = w*4 .. w*4+3, stage bf16 hi/lo ----
#pragma unroll
  for (int i=0;i<4;++i){
    const int sl = w*4 + i;
    float4 m0, m1;
    build_mix_row(bh, h, s0+sl, lane, score_ln, gamma, U, V, A_soft, m0, m1);
    float xs[8] = {m0.x,m0.y,m0.z,m0.w,m1.x,m1.y,m1.z,m1.w};
    unsigned short hv[8], lv[8];
#pragma unroll
    for (int j=0;j<8;++j){
      hv[j] = f2bf(xs[j]);
      lv[j] = f2bf(xs[j] - bf2f(hv[j]));
    }
    uint4 H4, L4;
    H4.x=(unsigned)hv[0]|((unsigned)hv[1]<<16); H4.y=(unsigned)hv[2]|((unsigned)hv[3]<<16);
    H4.z=(unsigned)hv[4]|((unsigned)hv[5]<<16); H4.w=(unsigned)hv[6]|((unsigned)hv[7]<<16);
    L4.x=(unsigned)lv[0]|((unsigned)lv[1]<<16); L4.y=(unsigned)lv[2]|((unsigned)lv[3]<<16);
    L4.z=(unsigned)lv[4]|((unsigned)lv[5]<<16); L4.w=(unsigned)lv[6]|((unsigned)lv[7]<<16);
    const unsigned byt = (unsigned)(sl*1024 + lane*16) ^ (unsigned)((sl&15)<<4);
    *(uint4*)(Abuf + byt)          = H4;
    *(uint4*)(Abuf + 32768 + byt)  = L4;
  }
  __syncthreads();   // drains everything incl. stage(0)

  // ---- phase 2: wave (stile,ntile) computes 16s x 16d, K=512 ----
  const int stile = w>>2, ntile = w&3;
  const int srow  = stile*16 + (lane&15);
  const unsigned sw = (unsigned)((lane&15)<<4);
  const unsigned a0off = (unsigned)(srow*1024 + ((lane>>4)*16));
  const int d    = ntile*16 + (lane&15);
  const int sgr  = lane>>4;
  const unsigned offH = (unsigned)(d*128 + ((sgr    ) ^ (d&7))*16);
  const unsigned offL = (unsigned)(d*128 + ((sgr + 4) ^ (d&7))*16);

  f32x4 acc0 = {0.f,0.f,0.f,0.f};
  f32x4 acc1 = {0.f,0.f,0.f,0.f};

#pragma unroll
  for (int t=0;t<16;++t){
    if (t > 0){
      asm volatile("s_waitcnt vmcnt(0) lgkmcnt(0)" ::: "memory");
      __builtin_amdgcn_s_barrier();
    }
    if (t < 15)
      gload16(sp + (size_t)(t+1)*32, &Bbuf[(t+1)&1][(unsigned)w<<10]);
    const unsigned ax = (a0off + (unsigned)(t*64)) ^ sw;
    bf16x8 ah = *(const bf16x8*)(Abuf + ax);
    bf16x8 al = *(const bf16x8*)(Abuf + 32768 + ax);
    const unsigned char* bb = Bbuf[t&1];
    bf16x8 bhv = *(const bf16x8*)(bb + offH);
    bf16x8 blv = *(const bf16x8*)(bb + offL);
    __builtin_amdgcn_s_setprio(1);
    acc0 = __builtin_amdgcn_mfma_f32_16x16x32_bf16(ah, bhv, acc0, 0, 0, 0);
    acc1 = __builtin_amdgcn_mfma_f32_16x16x32_bf16(al, bhv, acc1, 0, 0, 0);
    acc1 = __builtin_amdgcn_mfma_f32_16x16x32_bf16(ah, blv, acc1, 0, 0, 0);
    __builtin_amdgcn_s_setprio(0);
  }

  // ---- epilogue: stage f32 tile in Abuf, write full 128B lines ----
  __syncthreads();                      // all Abuf/Bbuf reads retired
  float* ob = (float*)Abuf;             // [32 s][64 d]
  const int m0r = stile*16 + (lane>>4)*4;
#pragma unroll
  for (int r=0;r<4;++r)
    ob[(m0r + r)*64 + d] = acc0[r] + acc1[r];
  __syncthreads();
  {
    const int row = tid >> 4;           // 0..31
    const int col = (tid & 15)*4;       // 0..60
    *(float4*)&out[(((size_t)b*SS + s0 + row)*HH + h)*DD + col]
        = *(const float4*)&ob[row*64 + col];
  }
}

// ---------- deep fallback: r1 LDS-broadcast kernel ----------
__global__ __launch_bounds__(512) void k_main_lds(const float* __restrict__ values,
    const float* __restrict__ alpha, const float* __restrict__ gamma,
    const float* __restrict__ U, const float* __restrict__ V,
    const float* __restrict__ score_ln, float* __restrict__ out)
{
  const int nwg = BB*HH*(SS/ROWS);
  const int bid = (blockIdx.x & 7)*(nwg/8) + (blockIdx.x >> 3);
  const int blocksPerBH = SS / ROWS;
  const int bh = bid / blocksPerBH;
  const int s0 = (bid % blocksPerBH) * ROWS;
  const int b = bh / HH, h = bh % HH;
  const int tid = threadIdx.x, w = tid >> 6, lane = tid & 63;
  __shared__ float smix[ROWS][FF];

  {
    const int s = s0 + w;
    const int f0 = lane*8;
    const float* sr = score_ln + (size_t)bh*FF + f0;
    float4 sv0 = *(const float4*)sr;
    float4 sv1 = *(const float4*)(sr+4);
    const float g = gamma[h*SS + s];
    float dl[8] = {sv0.x+g, sv0.y+g, sv0.z+g, sv0.w+g,
                   sv1.x+g, sv1.y+g, sv1.z+g, sv1.w+g};
    const float* Ur = U + ((size_t)h*SS + s)*RANKK;
    const float* Vh = V + (size_t)h*RANKK*FF + f0;
#pragma unroll
    for (int r=0;r<RANKK;++r){
      float u = Ur[r];
      float4 b0 = *(const float4*)(Vh + r*FF);
      float4 b1 = *(const float4*)(Vh + r*FF + 4);
      dl[0] += u*b0.x; dl[1] += u*b0.y; dl[2] += u*b0.z; dl[3] += u*b0.w;
      dl[4] += u*b1.x; dl[5] += u*b1.y; dl[6] += u*b1.z; dl[7] += u*b1.w;
    }
    topk_softmax8(dl);
    const float SCALE = (float)(1.0/sqrt((double)FF));
    const float* arow = alpha + ((size_t)h*SS + s)*FF + f0;
    float4 a0 = *(const float4*)arow;
    float4 a1 = *(const float4*)(arow+4);
    float ap[8] = {a0.x*SCALE, a0.y*SCALE, a0.z*SCALE, a0.w*SCALE,
                   a1.x*SCALE, a1.y*SCALE, a1.z*SCALE, a1.w*SCALE};
    topk_softmax8(ap);
    float4 m0 = make_float4(dl[0]+ap[0], dl[1]+ap[1], dl[2]+ap[2], dl[3]+ap[3]);
    float4 m1 = make_float4(dl[4]+ap[4], dl[5]+ap[5], dl[6]+ap[6], dl[7]+ap[7]);
    *(float4*)&smix[w][f0]   = m0;
    *(float4*)&smix[w][f0+4] = m1;
  }
  __syncthreads();

  float acc[ROWS] = {0,0,0,0,0,0,0,0};
  {
    const float* vp = values + (size_t)b*FF*HH*DD + (size_t)h*DD + lane;
#pragma unroll
    for (int i=0;i<16;++i){
      const int f0 = w*64 + i*4;
      float x0 = vp[(size_t)(f0+0)*HH*DD];
      float x1 = vp[(size_t)(f0+1)*HH*DD];
      float x2 = vp[(size_t)(f0+2)*HH*DD];
      float x3 = vp[(size_t)(f0+3)*HH*DD];
#pragma unroll
      for (int r=0;r<ROWS;++r){
        float4 m = *(const float4*)&smix[r][f0];
        acc[r] += m.x*x0 + m.y*x1 + m.z*x2 + m.w*x3;
      }
    }
  }
  __syncthreads();

  float* red = &smix[0][0];
#pragma unroll
  for (int r=0;r<ROWS;++r) red[(w*ROWS + r)*64 + lane] = acc[r];
  __syncthreads();
  {
    const int r = w, dd = lane;
    float sum = 0.f;
#pragma unroll
    for (int g=0; g<8; ++g) sum += red[(g*ROWS + r)*64 + dd];
    out[(((size_t)b*SS + s0 + r)*HH + h)*DD + dd] = sum;
  }
}

extern "C" void kernel_launch(void* const* d_in, const int* in_sizes, int n_in,
                              void* d_out, int out_size, void* d_ws, size_t ws_size,
                              hipStream_t stream) {
  const float* values = (const float*)d_in[0];
  const float* alpha  = (const float*)d_in[1];
  const float* temp   = (const float*)d_in[2];
  const float* gamma  = (const float*)d_in[3];
  const float* U      = (const float*)d_in[4];
  const float* V      = (const float*)d_in[5];
  const float* ln_w   = (const float*)d_in[6];
  const float* ln_b   = (const float*)d_in[7];
  float* out = (float*)d_out;
  float* ws  = (float*)d_ws;

  const size_t scoreN = (size_t)BB*HH*FF;             // 65,536 floats
  const size_t alphaN = (size_t)HH*SS*FF;             // 2,097,152 floats
  const size_t planeN = (size_t)BB*HH*DD*FF;          // 4,194,304 ushorts/plane

  float* score_ln = ws;
  float* A_soft   = ws + scoreN;
  unsigned short* hiP = (unsigned short*)(ws + scoreN + alphaN);
  unsigned short* loP = hiP + planeN;

  const size_t needFull = scoreN*4 + alphaN*4 + 2*planeN*2;   // 25.4 MB (proven)

  if (ws_size >= needFull){
    hipLaunchKernelGGL(k_prep_all, dim3(BB*HH + HH*SS/ROWS), dim3(512), 0, stream,
                       values, temp, ln_w, ln_b, alpha, score_ln, hiP, loP, A_soft);
    hipLaunchKernelGGL((k_mfma_t<BB>), dim3(HH*16*BB), dim3(512), 0, stream,
                       hiP, loP, gamma, U, V, score_ln, A_soft, out, 0);
  } else {
    hipLaunchKernelGGL(k_score, dim3(BB*HH), dim3(512), 0, stream,
                       values, temp, ln_w, ln_b, score_ln);
    hipLaunchKernelGGL(k_main_lds, dim3(BB*HH*(SS/ROWS)), dim3(512), 0, stream,
                       values, alpha, gamma, U, V, score_ln, out);
  }
}